// Round 1
// baseline (109.331 us; speedup 1.0000x reference)
//
#include <hip/hip_runtime.h>
#include <hip/hip_fp16.h>

// GraphConv on MI355X — round 8.
// vs round 7: weight matrices are pre-packed into fp16 MFMA B-fragment layout
// in the workspace by a tiny prep kernel (runs in the same graph, same stream).
// The fused kernel's ~200 scalar f32 weight loads + ~150 cvt_pk packs per wave
// become ~25 coalesced global_load_dwordx4, shortening the load->pack->MFMA
// dependency chains that dominate the latency-bound residual.

typedef _Float16 hf;
typedef __attribute__((ext_vector_type(8))) _Float16 v8hf;  // 4 VGPRs, MFMA A/B
typedef __attribute__((ext_vector_type(4))) float fv4;      // MFMA accumulator

union ABh { v8hf v; __half2 h[4]; };

// ---- weight prep: f32 weights -> fp16 MFMA B-fragments in workspace ----
// fragment f, lane l: ws[(f*64 + l)*8 .. +7]  (one dwordx4 per lane)
//   f  0..15 : W1   enc=f>>3, kk=(f>>2)&1 (0=P rows 0-15, 1=Q rows 16-31), ht=f&3
//              quads 2-3 zeroed (A is zero there too; avoids 0*NaN).
//   f 16..31 : W2   enc=(f-16)>>3, kk=(f>>2)&1 (K blocks of 32), ht=f&3
//   f 32..43 : ndw1 kk=(f-32)>>2 (0..2), ht=f&3; rows >=80 zeroed
//   f 44..45 : ndw2 kk=f-44
__global__ void prep_weights(const float* __restrict__ e0w1, const float* __restrict__ e0w2,
                             const float* __restrict__ e1w1, const float* __restrict__ e1w2,
                             const float* __restrict__ ndw1, const float* __restrict__ ndw2,
                             hf* __restrict__ ws)
{
  int g = blockIdx.x * 256 + threadIdx.x;
  if (g >= 46 * 64) return;
  int f = g >> 6, lane = g & 63;
  int quad = lane >> 4, col = lane & 15;
  v8hf h;
#pragma unroll
  for (int j = 0; j < 8; ++j) {
    float v = 0.f;
    if (f < 16) {
      const float* w1 = (f & 8) ? e1w1 : e0w1;
      int kk = (f >> 2) & 1, ht = f & 3;
      if (quad < 2) v = w1[(kk*16 + quad*8 + j)*64 + ht*16 + col];
    } else if (f < 32) {
      const float* w2 = ((f - 16) & 8) ? e1w2 : e0w2;
      int kk = (f >> 2) & 1, ht = f & 3;
      v = w2[(kk*32 + quad*8 + j)*64 + ht*16 + col];
    } else if (f < 44) {
      int kk = (f - 32) >> 2, ht = f & 3;
      int r = kk*32 + quad*8 + j;
      if (r < 80) v = ndw1[r*64 + ht*16 + col];
    } else {
      int kk = f - 44;
      v = ndw2[(kk*32 + quad*8 + j)*16 + col];
    }
    h[j] = (hf)v;
  }
  *(v8hf*)(ws + (size_t)g * 8) = h;
}

// grid = 128 b * 8 recv-groups, 256 threads (4 waves).
__global__ __launch_bounds__(256, 4) void fused_kernel(
    const float* __restrict__ ns, const float* __restrict__ et,
    const float* __restrict__ e0b1, const float* __restrict__ e1b1,
    const float* __restrict__ e0b2, const float* __restrict__ e1b2,
    const float* __restrict__ ndb1, const float* __restrict__ ndb2,
    const hf* __restrict__ wsf, float* __restrict__ out)
{
  __shared__ __align__(16) _Float16 PlH[2*64*72];   // 18432 B  P partials
  __shared__ __align__(16) _Float16 QbH[2*8*64];    //  2048 B  Q + b1
  __shared__ float ETl[2*8*64];                     //  4096 B  edge weights
  // XDH: rows 0-7 = XD ([ns(16) | msg(64) | 0(16)] stride 104);
  //      rows 8-23 = HD2 (decoder hidden, 16 rows so garbage reads stay in-bounds)
  __shared__ __align__(16) _Float16 XDH[24*104];    //  4992 B
  _Float16* XD  = XDH;
  _Float16* HD2 = XDH + 8*104;

  int t = threadIdx.x;
  int b = blockIdx.x >> 3, rg = blockIdx.x & 7, r0 = rg*8;
  int w = t >> 6, lane = t & 63, quad = lane >> 4, col = lane & 15;
  const v8hf* WF = (const v8hf*)wsf;

  const __half2 z2 = __float22half2_rn(make_float2(0.f, 0.f));
  const v8hf zero8 = {};

  // ======== early global loads (latency overlapped with P/Q MFMAs) ========
  float xnv = 0.f;
  if (t < 128) xnv = ns[(b*64 + r0 + (t >> 4))*16 + (t & 15)];
  float ev0[2], ev1[2];
  int es[2], erl[2];
#pragma unroll
  for (int i = 0; i < 2; ++i) {
    int idx = i*256 + t;                  // 0..511 -> (s, rl)
    int s = idx >> 3, rl = idx & 7;
    es[i] = s; erl[i] = rl;
    int r = r0 + rl;
    float v0 = 0.f, v1 = 0.f;
    if (s != r) {
      int pos = r - (r > s ? 1 : 0);
      const float* base = et + (b*4032 + s*63 + pos)*3;
      v0 = base[1]; v1 = base[2];
    }
    ev0[i] = v0; ev1[i] = v1;
  }

  // ======== P and Q via MFMA: node-tile @ W1 (64x64x16, K padded to 32) ====
  // wave w owns nodes w*16..w*16+15. B-fragments come pre-packed from ws.
  {
    ABh a;
    if (quad < 2) {
      const float* xr = ns + (b*64 + w*16 + col)*16 + quad*8;
      float4 x0 = *(const float4*)xr;
      float4 x1 = *(const float4*)(xr + 4);
      a.h[0] = __float22half2_rn(make_float2(x0.x, x0.y));
      a.h[1] = __float22half2_rn(make_float2(x0.z, x0.w));
      a.h[2] = __float22half2_rn(make_float2(x1.x, x1.y));
      a.h[3] = __float22half2_rn(make_float2(x1.z, x1.w));
    } else {
      a.h[0] = a.h[1] = a.h[2] = a.h[3] = z2;
    }
    bool qwave = (w == (rg >> 1));        // this wave's tile contains r0..r0+7
#pragma unroll
    for (int enc = 0; enc < 2; ++enc) {
      const float* b1 = enc ? e1b1 : e0b1;
#pragma unroll
      for (int ht = 0; ht < 4; ++ht) {
        int cc = ht*16 + col;
        v8hf bb = WF[(enc*8 + ht)*64 + lane];
        fv4 acc = {0.f, 0.f, 0.f, 0.f};
        acc = __builtin_amdgcn_mfma_f32_16x16x32_f16(a.v, bb, acc, 0, 0, 0);
        hf* pd = PlH + enc*4608 + (w*16 + quad*4)*72 + cc;
        pd[0*72] = (hf)acc[0];
        pd[1*72] = (hf)acc[1];
        pd[2*72] = (hf)acc[2];
        pd[3*72] = (hf)acc[3];
      }
      if (qwave) {                        // Q tile: W1 bottom rows 16..31
#pragma unroll
        for (int ht = 0; ht < 4; ++ht) {
          int cc = ht*16 + col;
          v8hf bb = WF[(enc*8 + 4 + ht)*64 + lane];
          fv4 acc = {0.f, 0.f, 0.f, 0.f};
          acc = __builtin_amdgcn_mfma_f32_16x16x32_f16(a.v, bb, acc, 0, 0, 0);
          float b1v = b1[cc];
#pragma unroll
          for (int rr = 0; rr < 4; ++rr) {
            int local = quad*4 + rr;      // node = w*16 + local
            if ((local >> 3) == (rg & 1)) // rows r0..r0+7 of this tile
              QbH[enc*512 + (local & 7)*64 + cc] = (hf)(acc[rr] + b1v);
          }
        }
      }
    }
  }
  // ---- store staged globals to LDS ----
  if (t < 128) {
    int rl = t >> 4, k = t & 15;
    XD[rl*104 + k] = (hf)xnv;             // ns part
    XD[rl*104 + 80 + k] = (hf)0.f;        // zero pad cols 80..95
  }
#pragma unroll
  for (int i = 0; i < 2; ++i) {
    ETl[erl[i]*64 + es[i]] = ev0[i];
    ETl[512 + erl[i]*64 + es[i]] = ev1[i];
  }
  __syncthreads();                        // barrier #1

  // ======== main loop: h2 = relu(h1 @ W2 + b2), et-weighted sum ========
  float msgacc[2][4] = {{0.f,0.f,0.f,0.f},{0.f,0.f,0.f,0.f}};

#pragma unroll 1
  for (int enc = 0; enc < 2; ++enc) {
    const float* b2 = enc ? e1b2 : e0b2;
    v8hf bfr[4][2];
    float b2v[4];
#pragma unroll
    for (int nt = 0; nt < 4; ++nt) {
      bfr[nt][0] = WF[(16 + enc*8 + nt)*64 + lane];
      bfr[nt][1] = WF[(16 + enc*8 + 4 + nt)*64 + lane];
      b2v[nt] = b2[nt*16 + col];
    }
#pragma unroll 1
    for (int rli = 0; rli < 2; ++rli) {
      int rl = w*2 + rli;                 // this wave owns receivers 2w, 2w+1
      const hf* qrow = QbH + (enc*8 + rl)*64;
      v8hf q0 = *(const v8hf*)(qrow + quad*8);
      v8hf q1 = *(const v8hf*)(qrow + 32 + quad*8);
      const float* etrow = ETl + (enc*8 + rl)*64;
#pragma unroll 2
      for (int st = 0; st < 4; ++st) {
        const hf* prow = PlH + enc*4608 + (st*16 + col)*72 + quad*8;
        v8hf p0 = *(const v8hf*)prow;
        v8hf p1 = *(const v8hf*)(prow + 32);
        v8hf s0 = __builtin_elementwise_max(p0 + q0, zero8);
        v8hf s1 = __builtin_elementwise_max(p1 + q1, zero8);
        float4 etv = *(const float4*)(etrow + st*16 + quad*4);
#pragma unroll
        for (int nt = 0; nt < 4; ++nt) {
          fv4 acc = {b2v[nt], b2v[nt], b2v[nt], b2v[nt]};
          acc = __builtin_amdgcn_mfma_f32_16x16x32_f16(s0, bfr[nt][0], acc, 0, 0, 0);
          acc = __builtin_amdgcn_mfma_f32_16x16x32_f16(s1, bfr[nt][1], acc, 0, 0, 0);
          float m = msgacc[rli][nt];
          m += etv.x * fmaxf(acc[0], 0.f);
          m += etv.y * fmaxf(acc[1], 0.f);
          m += etv.z * fmaxf(acc[2], 0.f);
          m += etv.w * fmaxf(acc[3], 0.f);
          msgacc[rli][nt] = m;
        }
      }
    }
  }
  // quad reduction over senders -> XD msg part (fp16)
#pragma unroll
  for (int rli = 0; rli < 2; ++rli) {
#pragma unroll
    for (int nt = 0; nt < 4; ++nt) {
      float v = msgacc[rli][nt];
      v += __shfl_xor(v, 16);
      v += __shfl_xor(v, 32);
      if (lane < 16) XD[(w*2 + rli)*104 + 16 + nt*16 + lane] = (hf)v;
    }
  }
  __syncthreads();                        // barrier #2

  // ======== decoder via MFMA, wave 0 only ========
  // layer1: C[m=rl][n] = XD(8x96) @ ndw1(96x64, rows>=80 zero), +b1, relu
  // layer2: C[m=rl][o] = HD2(8x64) @ ndw2(64x16), +b2, relu -> out
  if (w == 0) {
    v8hf xa[3];
    const hf* xrow = XD + col*104;        // A row = receiver rl (rows 8-15 garbage, unused)
#pragma unroll
    for (int kk = 0; kk < 3; ++kk) xa[kk] = *(const v8hf*)(xrow + kk*32 + quad*8);
#pragma unroll
    for (int ht = 0; ht < 4; ++ht) {
      int cc = ht*16 + col;
      float bias = ndb1[cc];
      fv4 acc = {bias, bias, bias, bias};
#pragma unroll
      for (int kk = 0; kk < 3; ++kk) {
        v8hf bb = WF[(32 + kk*4 + ht)*64 + lane];
        acc = __builtin_amdgcn_mfma_f32_16x16x32_f16(xa[kk], bb, acc, 0, 0, 0);
      }
      if (quad < 2) {
#pragma unroll
        for (int rr = 0; rr < 4; ++rr)
          HD2[(quad*4 + rr)*104 + cc] = (hf)fmaxf(acc[rr], 0.f);
      }
    }
    // layer2 (same-wave LDS write->read: program order, no barrier needed)
    const hf* hrow = HD2 + col*104;
    v8hf ha0 = *(const v8hf*)(hrow + quad*8);
    v8hf ha1 = *(const v8hf*)(hrow + 32 + quad*8);
    v8hf b20 = WF[44*64 + lane];
    v8hf b21 = WF[45*64 + lane];
    float bias2 = ndb2[col];
    fv4 acc2 = {bias2, bias2, bias2, bias2};
    acc2 = __builtin_amdgcn_mfma_f32_16x16x32_f16(ha0, b20, acc2, 0, 0, 0);
    acc2 = __builtin_amdgcn_mfma_f32_16x16x32_f16(ha1, b21, acc2, 0, 0, 0);
    if (quad < 2) {
#pragma unroll
      for (int rr = 0; rr < 4; ++rr) {
        int rl = quad*4 + rr;
        out[(b*64 + r0 + rl)*16 + col] = fmaxf(acc2[rr], 0.f);
      }
    }
  }
}

extern "C" void kernel_launch(void* const* d_in, const int* in_sizes, int n_in,
                              void* d_out, int out_size, void* d_ws, size_t ws_size,
                              hipStream_t stream) {
  const float* ns   = (const float*)d_in[0];
  const float* et   = (const float*)d_in[1];
  const float* e0w1 = (const float*)d_in[2];
  const float* e0b1 = (const float*)d_in[3];
  const float* e0w2 = (const float*)d_in[4];
  const float* e0b2 = (const float*)d_in[5];
  const float* e1w1 = (const float*)d_in[6];
  const float* e1b1 = (const float*)d_in[7];
  const float* e1w2 = (const float*)d_in[8];
  const float* e1b2 = (const float*)d_in[9];
  const float* ndw1 = (const float*)d_in[10];
  const float* ndb1 = (const float*)d_in[11];
  const float* ndw2 = (const float*)d_in[12];
  const float* ndb2 = (const float*)d_in[13];

  hf* wsf = (hf*)d_ws;
  prep_weights<<<12, 256, 0, stream>>>(e0w1, e0w2, e1w1, e1w2, ndw1, ndw2, wsf);
  fused_kernel<<<1024, 256, 0, stream>>>(ns, et,
                                         e0b1, e1b1, e0b2, e1b2,
                                         ndb1, ndb2,
                                         (const hf*)wsf, (float*)d_out);
}